// Round 2
// baseline (11.946 us; speedup 1.0000x reference)
//
#include <hip/hip_runtime.h>

// One thread per row b. Row = (K=4) x (nb=16) f32 bits = 64 floats = 16 uint4.
// out layout: [ out (B,16) | carry (B,16) ] floats, concatenated.
__global__ __launch_bounds__(256) void sga_row_kernel(const uint4* __restrict__ x,
                                                      float* __restrict__ out,
                                                      int B) {
    int b = blockIdx.x * blockDim.x + threadIdx.x;
    if (b >= B) return;

    const uint4* xp = x + (size_t)b * 16;

    // Pack each k-row's 16 {0.0,1.0} floats into a 16-bit int.
    // 1.0f == 0x3F800000 -> bit 23 distinguishes 0/1.
    unsigned a0 = 0, a1 = 0, a2 = 0, a3 = 0;
    #pragma unroll
    for (int q = 0; q < 4; ++q) {
        uint4 v0 = xp[0 * 4 + q];
        uint4 v1 = xp[1 * 4 + q];
        uint4 v2 = xp[2 * 4 + q];
        uint4 v3 = xp[3 * 4 + q];
        int sh = q * 4;
        a0 |= (((v0.x >> 23) & 1u) << (sh + 0)) | (((v0.y >> 23) & 1u) << (sh + 1)) |
              (((v0.z >> 23) & 1u) << (sh + 2)) | (((v0.w >> 23) & 1u) << (sh + 3));
        a1 |= (((v1.x >> 23) & 1u) << (sh + 0)) | (((v1.y >> 23) & 1u) << (sh + 1)) |
              (((v1.z >> 23) & 1u) << (sh + 2)) | (((v1.w >> 23) & 1u) << (sh + 3));
        a2 |= (((v2.x >> 23) & 1u) << (sh + 0)) | (((v2.y >> 23) & 1u) << (sh + 1)) |
              (((v2.z >> 23) & 1u) << (sh + 2)) | (((v2.w >> 23) & 1u) << (sh + 3));
        a3 |= (((v3.x >> 23) & 1u) << (sh + 0)) | (((v3.y >> 23) & 1u) << (sh + 1)) |
              (((v3.z >> 23) & 1u) << (sh + 2)) | (((v3.w >> 23) & 1u) << (sh + 3));
    }

    unsigned tot = a0 + a1 + a2 + a3;

    unsigned s[4], c[4], a[4] = {a0, a1, a2, a3};
    #pragma unroll
    for (int k = 0; k < 4; ++k) {
        unsigned bb  = (tot - a[k]) & 0xFFFFu;   // residual bits
        unsigned sum = a[k] + bb;                // 17-bit
        unsigned sk  = sum & 0xFFFFu;            // sum bits
        unsigned cin = a[k] ^ bb ^ sk;           // carry-in bits (bit0==0)
        s[k] = sk;
        c[k] = (cin >> 1) | (((sum >> 16) & 1u) << 15);  // carry-out bits
    }

    // Vertical per-bit popcount over k=0..3 -> 3 bitplanes (count 0..4).
    auto vcount = [](const unsigned* v, unsigned& p0, unsigned& p1, unsigned& p2) {
        unsigned l01 = v[0] ^ v[1], h01 = v[0] & v[1];
        unsigned l23 = v[2] ^ v[3], h23 = v[2] & v[3];
        p0 = l01 ^ l23;
        unsigned cr = l01 & l23;
        p1 = h01 ^ h23 ^ cr;
        p2 = (h01 & h23) | (h01 & cr) | (h23 & cr);
    };
    unsigned sp0, sp1, sp2, cp0, cp1, cp2;
    vcount(s, sp0, sp1, sp2);
    vcount(c, cp0, cp1, cp2);

    float4* ov = reinterpret_cast<float4*>(out) + (size_t)b * 4;
    float4* cv = reinterpret_cast<float4*>(out) + ((size_t)B + b) * 4;

    #pragma unroll
    for (int q = 0; q < 4; ++q) {
        int i0 = q * 4;
        float4 o, ca;
        o.x = (float)(((sp0 >> (i0 + 0)) & 1u) | ((((sp1 >> (i0 + 0)) & 1u) << 1)) | ((((sp2 >> (i0 + 0)) & 1u) << 2))) * 0.25f;
        o.y = (float)(((sp0 >> (i0 + 1)) & 1u) | ((((sp1 >> (i0 + 1)) & 1u) << 1)) | ((((sp2 >> (i0 + 1)) & 1u) << 2))) * 0.25f;
        o.z = (float)(((sp0 >> (i0 + 2)) & 1u) | ((((sp1 >> (i0 + 2)) & 1u) << 1)) | ((((sp2 >> (i0 + 2)) & 1u) << 2))) * 0.25f;
        o.w = (float)(((sp0 >> (i0 + 3)) & 1u) | ((((sp1 >> (i0 + 3)) & 1u) << 1)) | ((((sp2 >> (i0 + 3)) & 1u) << 2))) * 0.25f;
        ca.x = (float)(((cp0 >> (i0 + 0)) & 1u) | ((((cp1 >> (i0 + 0)) & 1u) << 1)) | ((((cp2 >> (i0 + 0)) & 1u) << 2)));
        ca.y = (float)(((cp0 >> (i0 + 1)) & 1u) | ((((cp1 >> (i0 + 1)) & 1u) << 1)) | ((((cp2 >> (i0 + 1)) & 1u) << 2)));
        ca.z = (float)(((cp0 >> (i0 + 2)) & 1u) | ((((cp1 >> (i0 + 2)) & 1u) << 1)) | ((((cp2 >> (i0 + 2)) & 1u) << 2)));
        ca.w = (float)(((cp0 >> (i0 + 3)) & 1u) | ((((cp1 >> (i0 + 3)) & 1u) << 1)) | ((((cp2 >> (i0 + 3)) & 1u) << 2)));
        ov[q] = o;
        cv[q] = ca;
    }
}

extern "C" void kernel_launch(void* const* d_in, const int* in_sizes, int n_in,
                              void* d_out, int out_size, void* d_ws, size_t ws_size,
                              hipStream_t stream) {
    const uint4* x = (const uint4*)d_in[0];   // (B, 4, 16) f32 in {0,1}
    // d_in[1] (p) is unused by the reference — intentionally not read.
    float* out = (float*)d_out;
    int B = in_sizes[0] / 64;                 // 65536
    int threads = 256;
    int blocks = (B + threads - 1) / threads;
    sga_row_kernel<<<blocks, threads, 0, stream>>>(x, out, B);
}

// Round 3
// 10.460 us; speedup vs baseline: 1.1420x; 1.1420x over previous
//
#include <hip/hip_runtime.h>

// One thread per (b,k), t = b*4 + k; quads of lanes share one row b.
// out layout: [ out (B,16) | carry (B,16) ] floats, concatenated.

__device__ __forceinline__ unsigned qadd_xor1(unsigned v) {
    // quad_perm [1,0,3,2] = 0xB1 : swap within pairs
    return v + (unsigned)__builtin_amdgcn_update_dpp((int)v, (int)v, 0xB1, 0xF, 0xF, true);
}
__device__ __forceinline__ unsigned qadd_xor2(unsigned v) {
    // quad_perm [2,3,0,1] = 0x4E : swap pairs
    return v + (unsigned)__builtin_amdgcn_update_dpp((int)v, (int)v, 0x4E, 0xF, 0xF, true);
}

__global__ __launch_bounds__(256) void sga_kernel(const uint4* __restrict__ x,
                                                  float* __restrict__ out,
                                                  int BK) {
    int t = blockIdx.x * blockDim.x + threadIdx.x;

    // 64B contiguous per thread: 4 x uint4 (f32 bits; 1.0f has bit 23 set)
    const uint4* xp = x + (size_t)t * 4;
    uint4 v0 = xp[0], v1 = xp[1], v2 = xp[2], v3 = xp[3];

    unsigned a =
        (((v0.x >> 23) & 1u) << 0)  | (((v0.y >> 23) & 1u) << 1)  |
        (((v0.z >> 23) & 1u) << 2)  | (((v0.w >> 23) & 1u) << 3)  |
        (((v1.x >> 23) & 1u) << 4)  | (((v1.y >> 23) & 1u) << 5)  |
        (((v1.z >> 23) & 1u) << 6)  | (((v1.w >> 23) & 1u) << 7)  |
        (((v2.x >> 23) & 1u) << 8)  | (((v2.y >> 23) & 1u) << 9)  |
        (((v2.z >> 23) & 1u) << 10) | (((v2.w >> 23) & 1u) << 11) |
        (((v3.x >> 23) & 1u) << 12) | (((v3.y >> 23) & 1u) << 13) |
        (((v3.z >> 23) & 1u) << 14) | (((v3.w >> 23) & 1u) << 15);

    // group-of-4 total via DPP quad adds (stays within the quad)
    unsigned tot = qadd_xor2(qadd_xor1(a));
    unsigned bb  = (tot - a) & 0xFFFFu;   // residual bits

    unsigned sum = a + bb;                // 17-bit
    unsigned s   = sum & 0xFFFFu;         // sum bits
    unsigned cin = a ^ bb ^ s;            // carry-in bits (bit0 == 0)
    unsigned c   = (cin >> 1) | (((sum >> 16) & 1u) << 15);  // carry-out bits

    // spread 8 bits -> 8 nibbles of a u32 (count per nibble <= 4: never carries)
    auto spread8 = [](unsigned b) {
        unsigned u = (b | (b << 12)) & 0x000F000Fu;
        u = (u | (u << 6)) & 0x03030303u;
        u = (u | (u << 3)) & 0x11111111u;
        return u;
    };
    unsigned ss_lo = spread8(s & 0xFFu), ss_hi = spread8(s >> 8);
    unsigned cc_lo = spread8(c & 0xFFu), cc_hi = spread8(c >> 8);

    // per-bit sums over the 4 lanes of the quad — pure VALU DPP adds
    ss_lo = qadd_xor2(qadd_xor1(ss_lo));
    ss_hi = qadd_xor2(qadd_xor1(ss_hi));
    cc_lo = qadd_xor2(qadd_xor1(cc_lo));
    cc_hi = qadd_xor2(qadd_xor1(cc_hi));

    // lane k of the quad writes bit positions 4k..4k+3 of row b:
    // k=0 -> ss_lo nibbles 0..3, k=1 -> ss_lo nibbles 4..7, k=2,3 -> ss_hi
    unsigned sel_s = (t & 2) ? ss_hi : ss_lo;
    unsigned sel_c = (t & 2) ? cc_hi : cc_lo;
    int sh = (t & 1) * 16;

    float4 o, ca;
    o.x  = (float)((sel_s >> (sh + 0))  & 0xFu) * 0.25f;
    o.y  = (float)((sel_s >> (sh + 4))  & 0xFu) * 0.25f;
    o.z  = (float)((sel_s >> (sh + 8))  & 0xFu) * 0.25f;
    o.w  = (float)((sel_s >> (sh + 12)) & 0xFu) * 0.25f;
    ca.x = (float)((sel_c >> (sh + 0))  & 0xFu);
    ca.y = (float)((sel_c >> (sh + 4))  & 0xFu);
    ca.z = (float)((sel_c >> (sh + 8))  & 0xFu);
    ca.w = (float)((sel_c >> (sh + 12)) & 0xFu);

    // global float offset = b*16 + k*4 = 4t -> coalesced float4 stores
    float4* outv = reinterpret_cast<float4*>(out);
    outv[t]      = o;          // out   region
    outv[BK + t] = ca;         // carry region (starts at float4 index BK)
}

extern "C" void kernel_launch(void* const* d_in, const int* in_sizes, int n_in,
                              void* d_out, int out_size, void* d_ws, size_t ws_size,
                              hipStream_t stream) {
    const uint4* x = (const uint4*)d_in[0];   // (B, K=4, 16) f32 in {0,1}
    // d_in[1] (p) is unused by the reference — intentionally not read.
    float* out = (float*)d_out;
    int BK = in_sizes[0] / 16;                // B*K = 262144 (multiple of 256)
    int threads = 256;
    int blocks = BK / threads;
    sga_kernel<<<blocks, threads, 0, stream>>>(x, out, BK);
}